// Round 12
// baseline (524.972 us; speedup 1.0000x reference)
//
#include <hip/hip_runtime.h>

#define NTOP 256

typedef __attribute__((ext_vector_type(8))) short bf16x8;
typedef __attribute__((ext_vector_type(4))) float f32x4;

// round-to-nearest-even split of fp32 into bf16 hi/lo, packed (hi<<16)|lo
__device__ inline unsigned int packbf(float x) {
  unsigned int u = __float_as_uint(x);
  unsigned int r = (u + 0x7fffu + ((u >> 16) & 1u)) & 0xffff0000u;
  float res = x - __uint_as_float(r);
  unsigned int u2 = __float_as_uint(res);
  unsigned int r2 = u2 + 0x7fffu + ((u2 >> 16) & 1u);
  return r | (r2 >> 16);
}

__device__ inline float tanh_fast(float x) {
  float e = __expf(2.f * x);
  return 1.f - 2.f / (e + 1.f);
}

template <int CTRL>
__device__ inline float dpp_f(float v) {
  return __int_as_float(__builtin_amdgcn_update_dpp(
      0, __float_as_int(v), CTRL, 0xf, 0xf, true));
}

// reduce across 16-lane row; lane 15 holds the total
__device__ inline float red16(float v) {
  v += dpp_f<0xB1>(v);   // quad_perm xor1
  v += dpp_f<0x4E>(v);   // quad_perm xor2
  v += dpp_f<0x114>(v);  // row_shr:4
  v += dpp_f<0x118>(v);  // row_shr:8
  return v;
}

// ---------------------------------------------------------------- K1
// LDS-issue-minimal recurrence: 512 thr (8 waves). Each 16-lane row owns
// 8 outputs x all 256 k; lane (row,l15) covers k in {64i+4*l15+e}.
// Per wave per step: 4 multicast ds_read_b128 (contiguous 256-B spans,
// conflict-free) -> ~40 LDS wave-insts/step/CU (was 256 in R8/R11).
// Weights w[8][4] float4 = 128 regs/thread, loaded ONCE (waves_per_eu(2,2)
// -> 256-reg budget at 8 waves/CU). DPP reduce; lane15 tanh+writeback;
// Hpack export parallelized over tid<256 from fresh LDS.
__global__ __launch_bounds__(512)
__attribute__((amdgpu_waves_per_eu(2, 2)))
void rsbc_recur(
    const float* __restrict__ Wih, const float* __restrict__ Whh,
    const float* __restrict__ bih, const float* __restrict__ bhh,
    const float* __restrict__ h0, unsigned int* __restrict__ Hpack) {
  __shared__ float hbuf[2][NTOP];
  const int tid = threadIdx.x;
  const int w = tid >> 6, l = tid & 63;
  const int r16 = l >> 4, l15 = l & 15;
  const int R = w * 4 + r16;            // 0..31: output row-group
  const int j0 = R * 8;                 // owns outputs j0..j0+7
  const int kcol = 4 * l15;             // lane's k-column within 64-span

  float bb[8];
#pragma unroll
  for (int jj = 0; jj < 8; ++jj) bb[jj] = bih[j0 + jj] + bhh[j0 + jj];

  // wt[jj][i] = W[j0+jj][64i + kcol .. +4]   (W_ih; += W_hh after step 0)
  float4 wt[8][4];
#pragma unroll
  for (int jj = 0; jj < 8; ++jj)
#pragma unroll
    for (int i = 0; i < 4; ++i)
      wt[jj][i] = *reinterpret_cast<const float4*>(
          Wih + (j0 + jj) * NTOP + 64 * i + kcol);

  if (tid < NTOP) hbuf[0][tid] = h0[tid];
  __syncthreads();

  // one step: read hr, write hw (lane15 of each row writes 8 outputs)
  auto step = [&](const float* hr, float* hw) {
    float4 h4[4];
#pragma unroll
    for (int i = 0; i < 4; ++i)
      h4[i] = *reinterpret_cast<const float4*>(hr + 64 * i + kcol);
    float a[8];
#pragma unroll
    for (int jj = 0; jj < 8; ++jj) {
      float t = 0.f;
#pragma unroll
      for (int i = 0; i < 4; ++i) {
        t = fmaf(h4[i].x, wt[jj][i].x, t);
        t = fmaf(h4[i].y, wt[jj][i].y, t);
        t = fmaf(h4[i].z, wt[jj][i].z, t);
        t = fmaf(h4[i].w, wt[jj][i].w, t);
      }
      a[jj] = red16(t);
    }
    if (l15 == 15) {
#pragma unroll
      for (int jj = 0; jj < 8; ++jj)
        hw[j0 + jj] = tanh_fast(a[jj] + bb[jj]);
    }
  };

  // step 0 (B = W_ih): h0 -> h1
  step(hbuf[0], hbuf[1]);
  // Wc = W_ih + W_hh (thread-local; ready before the barrier releases)
#pragma unroll
  for (int jj = 0; jj < 8; ++jj)
#pragma unroll
    for (int i = 0; i < 4; ++i) {
      float4 t = *reinterpret_cast<const float4*>(
          Whh + (j0 + jj) * NTOP + 64 * i + kcol);
      wt[jj][i].x += t.x; wt[jj][i].y += t.y;
      wt[jj][i].z += t.z; wt[jj][i].w += t.w;
    }
  __syncthreads();

#pragma unroll 1
  for (int s = 1; s < 255; ++s) {
    const float* hr = hbuf[s & 1];
    float* hw = hbuf[(s + 1) & 1];
    // export h_s -> H row s-1 (parallel packbf; store issued early so the
    // ack lands before this step's closing barrier)
    if (tid < NTOP) Hpack[(s - 1) * NTOP + tid] = packbf(hr[tid]);
    step(hr, hw);
    __syncthreads();
  }
  // h_255 lives in hbuf[1] -> H row 254
  if (tid < NTOP) Hpack[254 * NTOP + tid] = packbf(hbuf[1][tid]);
}

// ---------------------------------------------------------------- K2
// R8's proven K2 (~119 us): bf16x3 MFMA GEMM (Z @ H^T) + sigmoid +
// stick-breaking, 512 thr (8 waves 2x4), BM=128, N=256, K in 4 chunks
// of 64, 144-B LDS row stride, loads-before-barrier pipelining, LDS eta
// epilogue with 4-thread/row segmented cumprod, full-line float4 stores.
// waves_per_eu(2,2): LDS caps at 1 block/CU anyway; 256-reg budget.
__global__ __launch_bounds__(512)
__attribute__((amdgpu_waves_per_eu(2, 2)))
void rsbc_gemm_sb(
    const float* __restrict__ z, const unsigned int* __restrict__ Hpack,
    float* __restrict__ out) {
  constexpr int AS = 72;   // A row stride (bf16 elems), 144 B
  constexpr int BS = 72;   // B row stride
  constexpr int ES = 260;  // eta row stride (floats)
  __shared__ __align__(16) char smem[135168];
  __shared__ float logtab[256];
  ushort* Ahi = reinterpret_cast<ushort*>(smem);
  ushort* Alo = Ahi + 128 * AS;
  ushort* Bhi = Alo + 128 * AS;
  ushort* Blo = Bhi + 256 * BS;
  float* eta = reinterpret_cast<float*>(smem);
  float* segT = eta + 128 * ES;

  const int tid = threadIdx.x;
  const size_t row0 = (size_t)blockIdx.x * 128;
  const int wid = tid >> 6, lane = tid & 63;
  const int wr = wid >> 2, wc = wid & 3;
  const int l15 = lane & 15, l4 = lane >> 4;

  if (tid < 255) logtab[tid] = logf((float)(255 - tid));

  f32x4 acc[4][4];
#pragma unroll
  for (int mt = 0; mt < 4; ++mt)
#pragma unroll
    for (int nt = 0; nt < 4; ++nt) acc[mt][nt] = (f32x4){0.f, 0.f, 0.f, 0.f};

  for (int kc = 0; kc < 4; ++kc) {
    const int kb = kc * 64;
    float4 zreg[4];
#pragma unroll
    for (int it = 0; it < 4; ++it) {
      int idx = tid + 512 * it;        // 0..2047
      int r = idx >> 4, q = idx & 15;  // r 0..127
      zreg[it] = *reinterpret_cast<const float4*>(
          z + (row0 + r) * NTOP + kb + 4 * q);
    }
    uint4 hreg[8];
#pragma unroll
    for (int it = 0; it < 8; ++it) {
      int idx = tid + 512 * it;        // 0..4095
      int r = idx >> 4, q = idx & 15;  // r 0..255
      hreg[it] = (r < 255)
                     ? *reinterpret_cast<const uint4*>(
                           Hpack + r * NTOP + kb + 4 * q)
                     : make_uint4(0u, 0u, 0u, 0u);
    }
    __syncthreads();                   // previous chunk's frag reads done
#pragma unroll
    for (int it = 0; it < 4; ++it) {
      int idx = tid + 512 * it;
      int r = idx >> 4, q = idx & 15;
      float4 v = zreg[it];
      unsigned int p0 = packbf(v.x), p1 = packbf(v.y),
                   p2 = packbf(v.z), p3 = packbf(v.w);
      *reinterpret_cast<ushort4*>(&Ahi[r * AS + 4 * q]) = make_ushort4(
          (ushort)(p0 >> 16), (ushort)(p1 >> 16),
          (ushort)(p2 >> 16), (ushort)(p3 >> 16));
      *reinterpret_cast<ushort4*>(&Alo[r * AS + 4 * q]) = make_ushort4(
          (ushort)(p0 & 0xffff), (ushort)(p1 & 0xffff),
          (ushort)(p2 & 0xffff), (ushort)(p3 & 0xffff));
    }
#pragma unroll
    for (int it = 0; it < 8; ++it) {
      int idx = tid + 512 * it;
      int r = idx >> 4, q = idx & 15;
      uint4 hv = hreg[it];
      *reinterpret_cast<ushort4*>(&Bhi[r * BS + 4 * q]) = make_ushort4(
          (ushort)(hv.x >> 16), (ushort)(hv.y >> 16),
          (ushort)(hv.z >> 16), (ushort)(hv.w >> 16));
      *reinterpret_cast<ushort4*>(&Blo[r * BS + 4 * q]) = make_ushort4(
          (ushort)(hv.x & 0xffff), (ushort)(hv.y & 0xffff),
          (ushort)(hv.z & 0xffff), (ushort)(hv.w & 0xffff));
    }
    __syncthreads();                   // staging visible
#pragma unroll
    for (int ks = 0; ks < 2; ++ks) {
      const int ko = ks * 32 + l4 * 8;
      bf16x8 afh[4], afl[4], bfh[4], bfl[4];
#pragma unroll
      for (int mt = 0; mt < 4; ++mt) {
        int r = 64 * wr + 16 * mt + l15;
        afh[mt] = *reinterpret_cast<const bf16x8*>(&Ahi[r * AS + ko]);
        afl[mt] = *reinterpret_cast<const bf16x8*>(&Alo[r * AS + ko]);
      }
#pragma unroll
      for (int nt = 0; nt < 4; ++nt) {
        int n = 64 * wc + 16 * nt + l15;
        bfh[nt] = *reinterpret_cast<const bf16x8*>(&Bhi[n * BS + ko]);
        bfl[nt] = *reinterpret_cast<const bf16x8*>(&Blo[n * BS + ko]);
      }
#pragma unroll
      for (int mt = 0; mt < 4; ++mt)
#pragma unroll
        for (int nt = 0; nt < 4; ++nt) {
          acc[mt][nt] = __builtin_amdgcn_mfma_f32_16x16x32_bf16(
              afh[mt], bfh[nt], acc[mt][nt], 0, 0, 0);
          acc[mt][nt] = __builtin_amdgcn_mfma_f32_16x16x32_bf16(
              afh[mt], bfl[nt], acc[mt][nt], 0, 0, 0);
          acc[mt][nt] = __builtin_amdgcn_mfma_f32_16x16x32_bf16(
              afl[mt], bfh[nt], acc[mt][nt], 0, 0, 0);
        }
    }
  }
  __syncthreads();                     // frag reads done; smem becomes eta

  // eta = sigmoid(logits) -> LDS   (C/D: col=lane&15, row=(lane>>4)*4+i)
#pragma unroll
  for (int mt = 0; mt < 4; ++mt) {
    int rbase = 64 * wr + 16 * mt + 4 * l4;
#pragma unroll
    for (int nt = 0; nt < 4; ++nt) {
      int c = 64 * wc + 16 * nt + l15;
#pragma unroll
      for (int i = 0; i < 4; ++i) {
        float x = acc[mt][nt][i];
        eta[(rbase + i) * ES + c] = 1.f / (1.f + __expf(-x));
      }
    }
  }
  __syncthreads();

  // stick-breaking: 4 threads per row, segmented cumprod
  const int r = tid >> 2, qk = tid & 3;
  const int kbeg = 64 * qk, kend = (qk == 3) ? 255 : 64 * qk + 64;
  float* er = &eta[r * ES];
  {
    float cp = 1.f;
#pragma unroll 4
    for (int k = kbeg; k < kend; ++k) {
      float x = er[k] - logtab[k];
      float zc = 1.f / (1.f + __expf(-x));
      zc = fminf(fmaxf(zc, 1.1754943508222875e-38f), 0.99999988079071045f);
      er[k] = zc * cp;
      cp *= 1.f - zc;
    }
    segT[r * 4 + qk] = cp;
  }
  __syncthreads();
  {
    float p = 1.f;
    if (qk > 0) p *= segT[r * 4 + 0];
    if (qk > 1) p *= segT[r * 4 + 1];
    if (qk > 2) p *= segT[r * 4 + 2];
    if (qk > 0) {
#pragma unroll 4
      for (int k = kbeg; k < kend; ++k) er[k] *= p;
    }
    if (qk == 3) er[255] = p * segT[r * 4 + 3];
  }
  __syncthreads();

  // coalesced store: 128 rows x 64 float4
#pragma unroll
  for (int it = 0; it < 16; ++it) {
    int idx = tid + 512 * it;          // 0..8191
    int rr = idx >> 6, cq = idx & 63;
    float4 vv = *reinterpret_cast<const float4*>(&eta[rr * ES + 4 * cq]);
    *reinterpret_cast<float4*>(&out[(row0 + rr) * NTOP + 4 * cq]) = vv;
  }
}

// ---------------------------------------------------------------- launch
extern "C" void kernel_launch(void* const* d_in, const int* in_sizes, int n_in,
                              void* d_out, int out_size, void* d_ws, size_t ws_size,
                              hipStream_t stream) {
  const float* z   = (const float*)d_in[0];
  const float* h0  = (const float*)d_in[1];
  const float* Wih = (const float*)d_in[2];
  const float* Whh = (const float*)d_in[3];
  const float* bih = (const float*)d_in[4];
  const float* bhh = (const float*)d_in[5];
  float* out = (float*)d_out;
  unsigned int* Hpack = (unsigned int*)d_ws;  // 255*256 uint32

  rsbc_recur<<<1, 512, 0, stream>>>(Wih, Whh, bih, bhh, h0, Hpack);
  const int nrows = out_size / NTOP;          // 131072
  const int blocks = nrows / 128;             // 1024
  rsbc_gemm_sb<<<blocks, 512, 0, stream>>>(z, Hpack, out);
}

// Round 13
// 396.284 us; speedup vs baseline: 1.3247x; 1.3247x over previous
//
#include <hip/hip_runtime.h>

#define NTOP 256

typedef __attribute__((ext_vector_type(8))) short bf16x8;
typedef __attribute__((ext_vector_type(4))) float f32x4;

// round-to-nearest-even split of fp32 into bf16 hi/lo, packed (hi<<16)|lo
__device__ inline unsigned int packbf(float x) {
  unsigned int u = __float_as_uint(x);
  unsigned int r = (u + 0x7fffu + ((u >> 16) & 1u)) & 0xffff0000u;
  float res = x - __uint_as_float(r);
  unsigned int u2 = __float_as_uint(res);
  unsigned int r2 = u2 + 0x7fffu + ((u2 >> 16) & 1u);
  return r | (r2 >> 16);
}

__device__ inline float tanh_fast(float x) {
  float e = __expf(2.f * x);
  return 1.f - 2.f / (e + 1.f);
}

template <int CTRL>
__device__ inline float dpp_f(float v) {
  return __int_as_float(__builtin_amdgcn_update_dpp(
      0, __float_as_int(v), CTRL, 0xf, 0xf, true));
}

// reduce across 16-lane row; lane 15 holds the total
__device__ inline float red16(float v) {
  v += dpp_f<0xB1>(v);   // quad_perm xor1
  v += dpp_f<0x4E>(v);   // quad_perm xor2
  v += dpp_f<0x114>(v);  // row_shr:4
  v += dpp_f<0x118>(v);  // row_shr:8
  return v;
}

// ---------------------------------------------------------------- K1
// 1024 thr / 16 waves. Each 16-lane row owns 4 outputs x all 256 k:
// wt[4][4] float4 = 64 floats/thread (sum over CU = exactly Wc, 256 KB
// of the 512 KB register file). Live set ~105 <= 128 cap at
// waves_per_eu(4,4). After Wc build, weights are PINNED with asm
// identity ("+v") — kills the compiler's reload-from-L2 remat (the
// mechanism behind R10/R12's regressions; scratch spill would now show
// in WRITE_SIZE). Per step: 4 multicast ds_read_b128 (256-B contiguous
// spans, conflict-free), 64 FMA, 4x red16 DPP, lane-15 tanh+writeback;
// Hpack export parallelized over tid<256.
__global__ __launch_bounds__(1024)
__attribute__((amdgpu_waves_per_eu(4, 4)))
void rsbc_recur(
    const float* __restrict__ Wih, const float* __restrict__ Whh,
    const float* __restrict__ bih, const float* __restrict__ bhh,
    const float* __restrict__ h0, unsigned int* __restrict__ Hpack) {
  __shared__ float hbuf[2][NTOP];
  const int tid = threadIdx.x;
  const int l15 = tid & 15;
  const int j0 = (tid >> 4) * 4;        // owns outputs j0..j0+3
  const int kcol = 4 * l15;             // k-column within each 64-span

  float bb[4];
#pragma unroll
  for (int jj = 0; jj < 4; ++jj) bb[jj] = bih[j0 + jj] + bhh[j0 + jj];

  // wt[jj][i] = W[j0+jj][64i + kcol .. +4]  (W_ih; += W_hh after step 0)
  float4 wt[4][4];
#pragma unroll
  for (int jj = 0; jj < 4; ++jj)
#pragma unroll
    for (int i = 0; i < 4; ++i)
      wt[jj][i] = *reinterpret_cast<const float4*>(
          Wih + (j0 + jj) * NTOP + 64 * i + kcol);

  if (tid < NTOP) hbuf[0][tid] = h0[tid];
  __syncthreads();

  // one step: read hr, write hw (lane15 of each row writes 4 outputs)
  auto step = [&](const float* hr, float* hw) {
    float4 h4[4];
#pragma unroll
    for (int i = 0; i < 4; ++i)
      h4[i] = *reinterpret_cast<const float4*>(hr + 64 * i + kcol);
    float a[4];
#pragma unroll
    for (int jj = 0; jj < 4; ++jj) {
      float t = 0.f;
#pragma unroll
      for (int i = 0; i < 4; ++i) {
        t = fmaf(h4[i].x, wt[jj][i].x, t);
        t = fmaf(h4[i].y, wt[jj][i].y, t);
        t = fmaf(h4[i].z, wt[jj][i].z, t);
        t = fmaf(h4[i].w, wt[jj][i].w, t);
      }
      a[jj] = red16(t);
    }
    if (l15 == 15) {
#pragma unroll
      for (int jj = 0; jj < 4; ++jj)
        hw[j0 + jj] = tanh_fast(a[jj] + bb[jj]);
    }
  };

  // step 0 (B = W_ih): h0 -> h1
  step(hbuf[0], hbuf[1]);
  // Wc = W_ih + W_hh, then PIN in registers (opaque to remat)
#pragma unroll
  for (int jj = 0; jj < 4; ++jj)
#pragma unroll
    for (int i = 0; i < 4; ++i) {
      float4 t = *reinterpret_cast<const float4*>(
          Whh + (j0 + jj) * NTOP + 64 * i + kcol);
      wt[jj][i].x += t.x; wt[jj][i].y += t.y;
      wt[jj][i].z += t.z; wt[jj][i].w += t.w;
      asm volatile("" : "+v"(wt[jj][i].x));
      asm volatile("" : "+v"(wt[jj][i].y));
      asm volatile("" : "+v"(wt[jj][i].z));
      asm volatile("" : "+v"(wt[jj][i].w));
    }
  __syncthreads();

#pragma unroll 1
  for (int s = 1; s < 255; ++s) {
    const float* hr = hbuf[s & 1];
    float* hw = hbuf[(s + 1) & 1];
    // export h_s -> H row s-1 (parallel; ack lands before the barrier)
    if (tid < NTOP) Hpack[(s - 1) * NTOP + tid] = packbf(hr[tid]);
    step(hr, hw);
    __syncthreads();
  }
  // h_255 lives in hbuf[1] -> H row 254
  if (tid < NTOP) Hpack[254 * NTOP + tid] = packbf(hbuf[1][tid]);
}

// ---------------------------------------------------------------- K2
// R8's proven K2 (~119 us): bf16x3 MFMA GEMM (Z @ H^T) + sigmoid +
// stick-breaking, 512 thr (8 waves 2x4), BM=128, N=256, K in 4 chunks
// of 64, 144-B LDS row stride, loads-before-barrier pipelining, LDS eta
// epilogue with 4-thread/row segmented cumprod, full-line float4 stores.
__global__ __launch_bounds__(512)
__attribute__((amdgpu_waves_per_eu(2, 2)))
void rsbc_gemm_sb(
    const float* __restrict__ z, const unsigned int* __restrict__ Hpack,
    float* __restrict__ out) {
  constexpr int AS = 72;   // A row stride (bf16 elems), 144 B
  constexpr int BS = 72;   // B row stride
  constexpr int ES = 260;  // eta row stride (floats)
  __shared__ __align__(16) char smem[135168];
  __shared__ float logtab[256];
  ushort* Ahi = reinterpret_cast<ushort*>(smem);
  ushort* Alo = Ahi + 128 * AS;
  ushort* Bhi = Alo + 128 * AS;
  ushort* Blo = Bhi + 256 * BS;
  float* eta = reinterpret_cast<float*>(smem);
  float* segT = eta + 128 * ES;

  const int tid = threadIdx.x;
  const size_t row0 = (size_t)blockIdx.x * 128;
  const int wid = tid >> 6, lane = tid & 63;
  const int wr = wid >> 2, wc = wid & 3;
  const int l15 = lane & 15, l4 = lane >> 4;

  if (tid < 255) logtab[tid] = logf((float)(255 - tid));

  f32x4 acc[4][4];
#pragma unroll
  for (int mt = 0; mt < 4; ++mt)
#pragma unroll
    for (int nt = 0; nt < 4; ++nt) acc[mt][nt] = (f32x4){0.f, 0.f, 0.f, 0.f};

  for (int kc = 0; kc < 4; ++kc) {
    const int kb = kc * 64;
    float4 zreg[4];
#pragma unroll
    for (int it = 0; it < 4; ++it) {
      int idx = tid + 512 * it;        // 0..2047
      int r = idx >> 4, q = idx & 15;  // r 0..127
      zreg[it] = *reinterpret_cast<const float4*>(
          z + (row0 + r) * NTOP + kb + 4 * q);
    }
    uint4 hreg[8];
#pragma unroll
    for (int it = 0; it < 8; ++it) {
      int idx = tid + 512 * it;        // 0..4095
      int r = idx >> 4, q = idx & 15;  // r 0..255
      hreg[it] = (r < 255)
                     ? *reinterpret_cast<const uint4*>(
                           Hpack + r * NTOP + kb + 4 * q)
                     : make_uint4(0u, 0u, 0u, 0u);
    }
    __syncthreads();                   // previous chunk's frag reads done
#pragma unroll
    for (int it = 0; it < 4; ++it) {
      int idx = tid + 512 * it;
      int r = idx >> 4, q = idx & 15;
      float4 v = zreg[it];
      unsigned int p0 = packbf(v.x), p1 = packbf(v.y),
                   p2 = packbf(v.z), p3 = packbf(v.w);
      *reinterpret_cast<ushort4*>(&Ahi[r * AS + 4 * q]) = make_ushort4(
          (ushort)(p0 >> 16), (ushort)(p1 >> 16),
          (ushort)(p2 >> 16), (ushort)(p3 >> 16));
      *reinterpret_cast<ushort4*>(&Alo[r * AS + 4 * q]) = make_ushort4(
          (ushort)(p0 & 0xffff), (ushort)(p1 & 0xffff),
          (ushort)(p2 & 0xffff), (ushort)(p3 & 0xffff));
    }
#pragma unroll
    for (int it = 0; it < 8; ++it) {
      int idx = tid + 512 * it;
      int r = idx >> 4, q = idx & 15;
      uint4 hv = hreg[it];
      *reinterpret_cast<ushort4*>(&Bhi[r * BS + 4 * q]) = make_ushort4(
          (ushort)(hv.x >> 16), (ushort)(hv.y >> 16),
          (ushort)(hv.z >> 16), (ushort)(hv.w >> 16));
      *reinterpret_cast<ushort4*>(&Blo[r * BS + 4 * q]) = make_ushort4(
          (ushort)(hv.x & 0xffff), (ushort)(hv.y & 0xffff),
          (ushort)(hv.z & 0xffff), (ushort)(hv.w & 0xffff));
    }
    __syncthreads();                   // staging visible
#pragma unroll
    for (int ks = 0; ks < 2; ++ks) {
      const int ko = ks * 32 + l4 * 8;
      bf16x8 afh[4], afl[4], bfh[4], bfl[4];
#pragma unroll
      for (int mt = 0; mt < 4; ++mt) {
        int r = 64 * wr + 16 * mt + l15;
        afh[mt] = *reinterpret_cast<const bf16x8*>(&Ahi[r * AS + ko]);
        afl[mt] = *reinterpret_cast<const bf16x8*>(&Alo[r * AS + ko]);
      }
#pragma unroll
      for (int nt = 0; nt < 4; ++nt) {
        int n = 64 * wc + 16 * nt + l15;
        bfh[nt] = *reinterpret_cast<const bf16x8*>(&Bhi[n * BS + ko]);
        bfl[nt] = *reinterpret_cast<const bf16x8*>(&Blo[n * BS + ko]);
      }
#pragma unroll
      for (int mt = 0; mt < 4; ++mt)
#pragma unroll
        for (int nt = 0; nt < 4; ++nt) {
          acc[mt][nt] = __builtin_amdgcn_mfma_f32_16x16x32_bf16(
              afh[mt], bfh[nt], acc[mt][nt], 0, 0, 0);
          acc[mt][nt] = __builtin_amdgcn_mfma_f32_16x16x32_bf16(
              afh[mt], bfl[nt], acc[mt][nt], 0, 0, 0);
          acc[mt][nt] = __builtin_amdgcn_mfma_f32_16x16x32_bf16(
              afl[mt], bfh[nt], acc[mt][nt], 0, 0, 0);
        }
    }
  }
  __syncthreads();                     // frag reads done; smem becomes eta

  // eta = sigmoid(logits) -> LDS   (C/D: col=lane&15, row=(lane>>4)*4+i)
#pragma unroll
  for (int mt = 0; mt < 4; ++mt) {
    int rbase = 64 * wr + 16 * mt + 4 * l4;
#pragma unroll
    for (int nt = 0; nt < 4; ++nt) {
      int c = 64 * wc + 16 * nt + l15;
#pragma unroll
      for (int i = 0; i < 4; ++i) {
        float x = acc[mt][nt][i];
        eta[(rbase + i) * ES + c] = 1.f / (1.f + __expf(-x));
      }
    }
  }
  __syncthreads();

  // stick-breaking: 4 threads per row, segmented cumprod
  const int r = tid >> 2, qk = tid & 3;
  const int kbeg = 64 * qk, kend = (qk == 3) ? 255 : 64 * qk + 64;
  float* er = &eta[r * ES];
  {
    float cp = 1.f;
#pragma unroll 4
    for (int k = kbeg; k < kend; ++k) {
      float x = er[k] - logtab[k];
      float zc = 1.f / (1.f + __expf(-x));
      zc = fminf(fmaxf(zc, 1.1754943508222875e-38f), 0.99999988079071045f);
      er[k] = zc * cp;
      cp *= 1.f - zc;
    }
    segT[r * 4 + qk] = cp;
  }
  __syncthreads();
  {
    float p = 1.f;
    if (qk > 0) p *= segT[r * 4 + 0];
    if (qk > 1) p *= segT[r * 4 + 1];
    if (qk > 2) p *= segT[r * 4 + 2];
    if (qk > 0) {
#pragma unroll 4
      for (int k = kbeg; k < kend; ++k) er[k] *= p;
    }
    if (qk == 3) er[255] = p * segT[r * 4 + 3];
  }
  __syncthreads();

  // coalesced store: 128 rows x 64 float4
#pragma unroll
  for (int it = 0; it < 16; ++it) {
    int idx = tid + 512 * it;          // 0..8191
    int rr = idx >> 6, cq = idx & 63;
    float4 vv = *reinterpret_cast<const float4*>(&eta[rr * ES + 4 * cq]);
    *reinterpret_cast<float4*>(&out[(row0 + rr) * NTOP + 4 * cq]) = vv;
  }
}

// ---------------------------------------------------------------- launch
extern "C" void kernel_launch(void* const* d_in, const int* in_sizes, int n_in,
                              void* d_out, int out_size, void* d_ws, size_t ws_size,
                              hipStream_t stream) {
  const float* z   = (const float*)d_in[0];
  const float* h0  = (const float*)d_in[1];
  const float* Wih = (const float*)d_in[2];
  const float* Whh = (const float*)d_in[3];
  const float* bih = (const float*)d_in[4];
  const float* bhh = (const float*)d_in[5];
  float* out = (float*)d_out;
  unsigned int* Hpack = (unsigned int*)d_ws;  // 255*256 uint32

  rsbc_recur<<<1, 1024, 0, stream>>>(Wih, Whh, bih, bhh, h0, Hpack);
  const int nrows = out_size / NTOP;          // 131072
  const int blocks = nrows / 128;             // 1024
  rsbc_gemm_sb<<<blocks, 512, 0, stream>>>(z, Hpack, out);
}

// Round 16
// 323.505 us; speedup vs baseline: 1.6228x; 1.2250x over previous
//
#include <hip/hip_runtime.h>

#define NTOP 256

typedef __attribute__((ext_vector_type(8))) short bf16x8;
typedef __attribute__((ext_vector_type(4))) float f32x4;

// round-to-nearest-even split of fp32 into bf16 hi/lo, packed (hi<<16)|lo
__device__ inline unsigned int packbf(float x) {
  unsigned int u = __float_as_uint(x);
  unsigned int r = (u + 0x7fffu + ((u >> 16) & 1u)) & 0xffff0000u;
  float res = x - __uint_as_float(r);
  unsigned int u2 = __float_as_uint(res);
  unsigned int r2 = u2 + 0x7fffu + ((u2 >> 16) & 1u);
  return r | (r2 >> 16);
}

__device__ inline float tanh_fast(float x) {
  float e = __expf(2.f * x);
  return 1.f - 2.f / (e + 1.f);
}

template <int CTRL>
__device__ inline float dpp_f(float v) {
  return __int_as_float(__builtin_amdgcn_update_dpp(
      0, __float_as_int(v), CTRL, 0xf, 0xf, true));
}

// ---------------------------------------------------------------- K1
// R8 exactly (best measured: 203 us): 1024 thr, j = tid>>2 (output),
// qt = tid&3 (k-quarter of 64), w[16] float4 (64 floats) per thread,
// 4 independent FMA chains, 1 barrier/step, per-step packbf export,
// DPP quad-perm reduce (VALU pipe), tanh_fast.
__global__ __launch_bounds__(1024)
__attribute__((amdgpu_waves_per_eu(4, 4)))
void rsbc_recur(
    const float* __restrict__ Wih, const float* __restrict__ Whh,
    const float* __restrict__ bih, const float* __restrict__ bhh,
    const float* __restrict__ h0, unsigned int* __restrict__ Hpack) {
  __shared__ float hA[4][68], hB[4][68];
  const int tid = threadIdx.x;
  const int j = tid >> 2, qt = tid & 3, k0 = qt * 64;
  const float bj = bih[j] + bhh[j];

  float4 w[16];
  {
    const float4* wp = reinterpret_cast<const float4*>(Wih + j * NTOP + k0);
#pragma unroll
    for (int q = 0; q < 16; ++q) w[q] = wp[q];
  }
  if (tid < NTOP) hA[tid >> 6][tid & 63] = h0[tid];
  __syncthreads();

  // step 0: h1 = tanh(h0 @ Wih^T + b)
  {
    const float* hq = hA[qt];
    float a0 = 0.f, a1 = 0.f, a2 = 0.f, a3 = 0.f;
#pragma unroll
    for (int q = 0; q < 16; ++q) {
      float4 hv = *reinterpret_cast<const float4*>(hq + 4 * q);
      a0 = fmaf(hv.x, w[q].x, a0);
      a1 = fmaf(hv.y, w[q].y, a1);
      a2 = fmaf(hv.z, w[q].z, a2);
      a3 = fmaf(hv.w, w[q].w, a3);
    }
    float sv = (a0 + a1) + (a2 + a3);
    sv += dpp_f<0xB1>(sv);  // + lane^1 (quad_perm 1,0,3,2)
    sv += dpp_f<0x4E>(sv);  // + lane^2 (quad_perm 2,3,0,1)
    if (qt == 0) {
      float v = tanh_fast(sv + bj);
      hB[j >> 6][j & 63] = v;
      Hpack[j] = packbf(v);            // H row 0
    }
  }
  // Wc = W_ih + W_hh
  {
    const float4* wq = reinterpret_cast<const float4*>(Whh + j * NTOP + k0);
#pragma unroll
    for (int q = 0; q < 16; ++q) {
      float4 t = wq[q];
      w[q].x += t.x; w[q].y += t.y; w[q].z += t.z; w[q].w += t.w;
    }
  }
  __syncthreads();

#pragma unroll 1
  for (int s = 1; s < 255; ++s) {
    const float(*hr)[68] = (s & 1) ? hB : hA;
    float(*hw)[68] = (s & 1) ? hA : hB;
    const float* hq = hr[qt];
    float a0 = 0.f, a1 = 0.f, a2 = 0.f, a3 = 0.f;
#pragma unroll
    for (int q = 0; q < 16; ++q) {
      float4 hv = *reinterpret_cast<const float4*>(hq + 4 * q);
      a0 = fmaf(hv.x, w[q].x, a0);
      a1 = fmaf(hv.y, w[q].y, a1);
      a2 = fmaf(hv.z, w[q].z, a2);
      a3 = fmaf(hv.w, w[q].w, a3);
    }
    float sv = (a0 + a1) + (a2 + a3);
    sv += dpp_f<0xB1>(sv);
    sv += dpp_f<0x4E>(sv);
    if (qt == 0) {
      float v = tanh_fast(sv + bj);
      hw[j >> 6][j & 63] = v;
      Hpack[s * NTOP + j] = packbf(v); // H row s
    }
    __syncthreads();
  }
}

// ---------------------------------------------------------------- K2
// R8's K2 exactly (best measured: ~119 us): bf16x3 MFMA GEMM (Z @ H^T)
// + sigmoid + stick-breaking, 512 thr (8 waves 2x4), BM=128, N=256,
// K in 4 chunks of 64, 144-B LDS row stride (conflict-light),
// loads-before-barrier pipelining, LDS eta epilogue with 4-thread/row
// segmented cumprod, full-line float4 stores.
__global__ __launch_bounds__(512)
__attribute__((amdgpu_waves_per_eu(2, 2)))
void rsbc_gemm_sb(
    const float* __restrict__ z, const unsigned int* __restrict__ Hpack,
    float* __restrict__ out) {
  constexpr int AS = 72;   // A row stride (bf16 elems), 144 B
  constexpr int BS = 72;   // B row stride
  constexpr int ES = 260;  // eta row stride (floats)
  __shared__ __align__(16) char smem[135168];
  __shared__ float logtab[256];
  ushort* Ahi = reinterpret_cast<ushort*>(smem);
  ushort* Alo = Ahi + 128 * AS;
  ushort* Bhi = Alo + 128 * AS;
  ushort* Blo = Bhi + 256 * BS;
  float* eta = reinterpret_cast<float*>(smem);
  float* segT = eta + 128 * ES;

  const int tid = threadIdx.x;
  const size_t row0 = (size_t)blockIdx.x * 128;
  const int wid = tid >> 6, lane = tid & 63;
  const int wr = wid >> 2, wc = wid & 3;
  const int l15 = lane & 15, l4 = lane >> 4;

  if (tid < 255) logtab[tid] = logf((float)(255 - tid));

  f32x4 acc[4][4];
#pragma unroll
  for (int mt = 0; mt < 4; ++mt)
#pragma unroll
    for (int nt = 0; nt < 4; ++nt) acc[mt][nt] = (f32x4){0.f, 0.f, 0.f, 0.f};

  for (int kc = 0; kc < 4; ++kc) {
    const int kb = kc * 64;
    // ---- global loads into regs (issued before barrier: overlap compute)
    float4 zreg[4];
#pragma unroll
    for (int it = 0; it < 4; ++it) {
      int idx = tid + 512 * it;        // 0..2047
      int r = idx >> 4, q = idx & 15;  // r 0..127
      zreg[it] = *reinterpret_cast<const float4*>(
          z + (row0 + r) * NTOP + kb + 4 * q);
    }
    uint4 hreg[8];
#pragma unroll
    for (int it = 0; it < 8; ++it) {
      int idx = tid + 512 * it;        // 0..4095
      int r = idx >> 4, q = idx & 15;  // r 0..255
      hreg[it] = (r < 255)
                     ? *reinterpret_cast<const uint4*>(
                           Hpack + r * NTOP + kb + 4 * q)
                     : make_uint4(0u, 0u, 0u, 0u);
    }
    __syncthreads();                   // previous chunk's frag reads done
    // ---- convert + LDS write
#pragma unroll
    for (int it = 0; it < 4; ++it) {
      int idx = tid + 512 * it;
      int r = idx >> 4, q = idx & 15;
      float4 v = zreg[it];
      unsigned int p0 = packbf(v.x), p1 = packbf(v.y),
                   p2 = packbf(v.z), p3 = packbf(v.w);
      *reinterpret_cast<ushort4*>(&Ahi[r * AS + 4 * q]) = make_ushort4(
          (ushort)(p0 >> 16), (ushort)(p1 >> 16),
          (ushort)(p2 >> 16), (ushort)(p3 >> 16));
      *reinterpret_cast<ushort4*>(&Alo[r * AS + 4 * q]) = make_ushort4(
          (ushort)(p0 & 0xffff), (ushort)(p1 & 0xffff),
          (ushort)(p2 & 0xffff), (ushort)(p3 & 0xffff));
    }
#pragma unroll
    for (int it = 0; it < 8; ++it) {
      int idx = tid + 512 * it;
      int r = idx >> 4, q = idx & 15;
      uint4 hv = hreg[it];
      *reinterpret_cast<ushort4*>(&Bhi[r * BS + 4 * q]) = make_ushort4(
          (ushort)(hv.x >> 16), (ushort)(hv.y >> 16),
          (ushort)(hv.z >> 16), (ushort)(hv.w >> 16));
      *reinterpret_cast<ushort4*>(&Blo[r * BS + 4 * q]) = make_ushort4(
          (ushort)(hv.x & 0xffff), (ushort)(hv.y & 0xffff),
          (ushort)(hv.z & 0xffff), (ushort)(hv.w & 0xffff));
    }
    __syncthreads();                   // staging visible
    // ---- compute: 2 k-steps of K=32
#pragma unroll
    for (int ks = 0; ks < 2; ++ks) {
      const int ko = ks * 32 + l4 * 8; // k elem offset within chunk row
      bf16x8 afh[4], afl[4], bfh[4], bfl[4];
#pragma unroll
      for (int mt = 0; mt < 4; ++mt) {
        int r = 64 * wr + 16 * mt + l15;
        afh[mt] = *reinterpret_cast<const bf16x8*>(&Ahi[r * AS + ko]);
        afl[mt] = *reinterpret_cast<const bf16x8*>(&Alo[r * AS + ko]);
      }
#pragma unroll
      for (int nt = 0; nt < 4; ++nt) {
        int n = 64 * wc + 16 * nt + l15;
        bfh[nt] = *reinterpret_cast<const bf16x8*>(&Bhi[n * BS + ko]);
        bfl[nt] = *reinterpret_cast<const bf16x8*>(&Blo[n * BS + ko]);
      }
#pragma unroll
      for (int mt = 0; mt < 4; ++mt)
#pragma unroll
        for (int nt = 0; nt < 4; ++nt) {
          acc[mt][nt] = __builtin_amdgcn_mfma_f32_16x16x32_bf16(
              afh[mt], bfh[nt], acc[mt][nt], 0, 0, 0);
          acc[mt][nt] = __builtin_amdgcn_mfma_f32_16x16x32_bf16(
              afh[mt], bfl[nt], acc[mt][nt], 0, 0, 0);
          acc[mt][nt] = __builtin_amdgcn_mfma_f32_16x16x32_bf16(
              afl[mt], bfh[nt], acc[mt][nt], 0, 0, 0);
        }
    }
  }
  __syncthreads();                     // frag reads done; smem becomes eta

  // ---- eta = sigmoid(logits) -> LDS
  // C/D layout (16x16x32): col = lane&15, row = (lane>>4)*4 + reg
#pragma unroll
  for (int mt = 0; mt < 4; ++mt) {
    int rbase = 64 * wr + 16 * mt + 4 * l4;
#pragma unroll
    for (int nt = 0; nt < 4; ++nt) {
      int c = 64 * wc + 16 * nt + l15;
#pragma unroll
      for (int i = 0; i < 4; ++i) {
        float x = acc[mt][nt][i];
        eta[(rbase + i) * ES + c] = 1.f / (1.f + __expf(-x));
      }
    }
  }
  __syncthreads();

  // ---- stick-breaking: 4 threads per row, segmented cumprod
  const int r = tid >> 2, qk = tid & 3;
  const int kbeg = 64 * qk, kend = (qk == 3) ? 255 : 64 * qk + 64;
  float* er = &eta[r * ES];
  {
    float cp = 1.f;
#pragma unroll 4
    for (int k = kbeg; k < kend; ++k) {
      float x = er[k] - logtab[k];
      float zc = 1.f / (1.f + __expf(-x));
      zc = fminf(fmaxf(zc, 1.1754943508222875e-38f), 0.99999988079071045f);
      er[k] = zc * cp;
      cp *= 1.f - zc;
    }
    segT[r * 4 + qk] = cp;
  }
  __syncthreads();
  {
    float p = 1.f;
    if (qk > 0) p *= segT[r * 4 + 0];
    if (qk > 1) p *= segT[r * 4 + 1];
    if (qk > 2) p *= segT[r * 4 + 2];
    if (qk > 0) {
#pragma unroll 4
      for (int k = kbeg; k < kend; ++k) er[k] *= p;
    }
    if (qk == 3) er[255] = p * segT[r * 4 + 3];
  }
  __syncthreads();

  // ---- coalesced store: 128 rows x 64 float4
#pragma unroll
  for (int it = 0; it < 16; ++it) {
    int idx = tid + 512 * it;          // 0..8191
    int rr = idx >> 6, cq = idx & 63;
    float4 vv = *reinterpret_cast<const float4*>(&eta[rr * ES + 4 * cq]);
    *reinterpret_cast<float4*>(&out[(row0 + rr) * NTOP + 4 * cq]) = vv;
  }
}

// ---------------------------------------------------------------- launch
extern "C" void kernel_launch(void* const* d_in, const int* in_sizes, int n_in,
                              void* d_out, int out_size, void* d_ws, size_t ws_size,
                              hipStream_t stream) {
  const float* z   = (const float*)d_in[0];
  const float* h0  = (const float*)d_in[1];
  const float* Wih = (const float*)d_in[2];
  const float* Whh = (const float*)d_in[3];
  const float* bih = (const float*)d_in[4];
  const float* bhh = (const float*)d_in[5];
  float* out = (float*)d_out;
  unsigned int* Hpack = (unsigned int*)d_ws;  // 255*256 uint32

  rsbc_recur<<<1, 1024, 0, stream>>>(Wih, Whh, bih, bhh, h0, Hpack);
  const int nrows = out_size / NTOP;          // 131072
  const int blocks = nrows / 128;             // 1024
  rsbc_gemm_sb<<<blocks, 512, 0, stream>>>(z, Hpack, out);
}